// Round 1
// baseline (592.923 us; speedup 1.0000x reference)
//
#include <hip/hip_runtime.h>

#define IN_F 8192
#define OUT_F 8192
#define THRESHOLD_F 50.0f
#define TARGET_RATE 0.1f

// clang-native vector type: required by __builtin_nontemporal_load/store
typedef float f32x4 __attribute__((ext_vector_type(4)));

// One WAVE per output row; 4 waves (4 rows) per 256-thread block; no LDS, no
// barriers. Each wave: reduce S row -> butterfly shuffle (all lanes get sum)
// -> spike -> stream E row -> trace row. Waves pipeline independently so the
// memory system never drains at a phase boundary.
//
// Cache-residency policy (this round's change):
//   S loads: REGULAR (allocate, evict-last). S is 268 MB ~= the 256 MB
//            Infinity Cache; under back-to-back replay it can stay resident
//            across iterations and hit in L3.
//   E loads: NONTEMPORAL (single-use stream; evict-first so it does not
//            displace the protected S working set).
//   T stores: NONTEMPORAL (never re-read; no-allocate).
__global__ __launch_bounds__(256) void snn_wave_fused(
    const float* __restrict__ spike_input,        // [IN_F]
    const float* __restrict__ synapse_states,     // [OUT_F, IN_F]
    const float* __restrict__ membrane_potential, // [OUT_F]
    const float* __restrict__ adaptive_threshold, // [OUT_F]
    const float* __restrict__ eligibility_trace,  // [OUT_F, IN_F]
    float* __restrict__ out_spikes,               // [OUT_F]
    float* __restrict__ out_vmem,                 // [OUT_F]
    float* __restrict__ out_thresh,               // [OUT_F]
    float* __restrict__ out_trace)                // [OUT_F, IN_F]
{
    const int row  = (blockIdx.x << 2) + (threadIdx.x >> 6);  // wave id = row
    const int lane = threadIdx.x & 63;

    const f32x4* x4 = (const f32x4*)spike_input;
    const f32x4* s4 = (const f32x4*)(synapse_states + (size_t)row * IN_F);

    // ---- Phase 1: current = sum_i (S[row,i] > 50) * clip(2*x[i],0,1) ----
    float sum = 0.0f;
    #pragma unroll 8
    for (int k = 0; k < 32; ++k) {
        int idx = lane + (k << 6);                 // f32x4 idx in [0, 2048)
        f32x4 s = s4[idx];                         // REGULAR: let L3 keep S across replays
        f32x4 v = x4[idx];                         // hot in L1/L2
        v.x = fminf(fmaxf(v.x * 2.0f, 0.0f), 1.0f);
        v.y = fminf(fmaxf(v.y * 2.0f, 0.0f), 1.0f);
        v.z = fminf(fmaxf(v.z * 2.0f, 0.0f), 1.0f);
        v.w = fminf(fmaxf(v.w * 2.0f, 0.0f), 1.0f);
        sum += (s.x > THRESHOLD_F ? v.x : 0.0f)
             + (s.y > THRESHOLD_F ? v.y : 0.0f)
             + (s.z > THRESHOLD_F ? v.z : 0.0f)
             + (s.w > THRESHOLD_F ? v.w : 0.0f);
    }
    // Butterfly reduction: every lane ends with the identical full sum
    #pragma unroll
    for (int m = 1; m < 64; m <<= 1)
        sum += __shfl_xor(sum, m, 64);

    // ---- Phase 2: neuron update (all lanes compute; lane 0 writes) ----
    float v_mem = membrane_potential[row] * 0.7f + sum;   // wave-broadcast load
    float thr   = adaptive_threshold[row];
    float spike = (v_mem >= thr) ? 1.0f : 0.0f;
    if (lane == 0) {
        out_spikes[row] = spike;
        out_vmem[row]   = v_mem * (1.0f - spike) * 0.3f;
        out_thresh[row] = fminf(fmaxf(thr + (spike - TARGET_RATE) * 0.05f, 0.5f), 5.0f);
    }

    // ---- Phase 3: new_trace[row,i] = clip(E*0.8 + spike*x, 0, 3) ----
    const f32x4* e4 = (const f32x4*)(eligibility_trace + (size_t)row * IN_F);
    f32x4* t4 = (f32x4*)(out_trace + (size_t)row * IN_F);
    #pragma unroll 8
    for (int k = 0; k < 32; ++k) {
        int idx = lane + (k << 6);
        f32x4 e = __builtin_nontemporal_load(&e4[idx]);  // stream: evict-first
        f32x4 v = x4[idx];
        f32x4 t;
        t.x = fminf(fmaxf(e.x * 0.8f + spike * fminf(fmaxf(v.x * 2.0f, 0.0f), 1.0f), 0.0f), 3.0f);
        t.y = fminf(fmaxf(e.y * 0.8f + spike * fminf(fmaxf(v.y * 2.0f, 0.0f), 1.0f), 0.0f), 3.0f);
        t.z = fminf(fmaxf(e.z * 0.8f + spike * fminf(fmaxf(v.z * 2.0f, 0.0f), 1.0f), 0.0f), 3.0f);
        t.w = fminf(fmaxf(e.w * 0.8f + spike * fminf(fmaxf(v.w * 2.0f, 0.0f), 1.0f), 0.0f), 3.0f);
        __builtin_nontemporal_store(t, &t4[idx]);   // streamed out, never re-read
    }
}

extern "C" void kernel_launch(void* const* d_in, const int* in_sizes, int n_in,
                              void* d_out, int out_size, void* d_ws, size_t ws_size,
                              hipStream_t stream) {
    const float* spike_input        = (const float*)d_in[0];
    const float* synapse_states     = (const float*)d_in[1];
    const float* membrane_potential = (const float*)d_in[2];
    const float* adaptive_threshold = (const float*)d_in[3];
    const float* eligibility_trace  = (const float*)d_in[4];

    float* out = (float*)d_out;
    float* out_spikes = out;                      // [OUT_F]
    float* out_vmem   = out + OUT_F;              // [OUT_F]
    float* out_thresh = out + 2 * OUT_F;          // [OUT_F]
    float* out_trace  = out + 3 * OUT_F;          // [OUT_F, IN_F]

    // 4 rows (waves) per block -> 2048 blocks.
    snn_wave_fused<<<OUT_F / 4, 256, 0, stream>>>(
        spike_input, synapse_states, membrane_potential, adaptive_threshold,
        eligibility_trace, out_spikes, out_vmem, out_thresh, out_trace);
}

// Round 5
// 583.639 us; speedup vs baseline: 1.0159x; 1.0159x over previous
//
#include <hip/hip_runtime.h>

#define IN_F 8192
#define OUT_F 8192
#define THRESHOLD_F 50.0f
#define TARGET_RATE 0.1f

// clang-native vector type: required by __builtin_nontemporal_load/store
typedef float f32x4 __attribute__((ext_vector_type(4)));

// ---------------------------------------------------------------------------
// Two-kernel homogeneous-stream split (round-4 resubmit; rounds 2-4 died on
// "container failed twice" with three structurally different kernels ->
// infra-flake diagnosis; this version additionally removes the one element
// common to all three failures, the data-dependent spike branch).
//
// Theory: round-0's fused kernel runs ~5.0 TB/s aggregate vs the 6.29 TB/s
// copy ceiling because each wave phase-switches (read-reduce -> vmcnt drain
// -> interleaved read/write tail). Splitting gives two copy-shaped kernels:
//   A: pure read stream (S) + tiny epilogue   -> read-only BW shape
//   B: pure 1:1 read/write stream (E -> T)    -> exactly the float4-copy shape
// Cache policy: everything nt (round-1 measured L3-residency for S SLOWER
// than the nt HBM stream: 202 us vs ~160 us).
// ---------------------------------------------------------------------------

// Kernel A: one wave per row; 4 waves per 256-thread block; no LDS/barriers.
// current = sum_i (S[row,i] > 50) * clip(2*x[i],0,1); spike/vmem/thresh out.
__global__ __launch_bounds__(256) void snn_reduce(
    const float* __restrict__ spike_input,        // [IN_F]
    const float* __restrict__ synapse_states,     // [OUT_F, IN_F]
    const float* __restrict__ membrane_potential, // [OUT_F]
    const float* __restrict__ adaptive_threshold, // [OUT_F]
    float* __restrict__ out_spikes,               // [OUT_F]
    float* __restrict__ out_vmem,                 // [OUT_F]
    float* __restrict__ out_thresh)               // [OUT_F]
{
    const int row  = (blockIdx.x << 2) + (threadIdx.x >> 6);  // wave id = row
    const int lane = threadIdx.x & 63;

    const f32x4* x4 = (const f32x4*)spike_input;
    const f32x4* s4 = (const f32x4*)(synapse_states + (size_t)row * IN_F);

    float sum = 0.0f;
    #pragma unroll 8
    for (int k = 0; k < 32; ++k) {
        int idx = lane + (k << 6);                 // f32x4 idx in [0, 2048)
        f32x4 s = __builtin_nontemporal_load(&s4[idx]);  // single-use stream
        f32x4 v = x4[idx];                               // hot in cache
        v.x = fminf(fmaxf(v.x * 2.0f, 0.0f), 1.0f);
        v.y = fminf(fmaxf(v.y * 2.0f, 0.0f), 1.0f);
        v.z = fminf(fmaxf(v.z * 2.0f, 0.0f), 1.0f);
        v.w = fminf(fmaxf(v.w * 2.0f, 0.0f), 1.0f);
        sum += (s.x > THRESHOLD_F ? v.x : 0.0f)
             + (s.y > THRESHOLD_F ? v.y : 0.0f)
             + (s.z > THRESHOLD_F ? v.z : 0.0f)
             + (s.w > THRESHOLD_F ? v.w : 0.0f);
    }
    // Butterfly reduction: every lane ends with the identical full sum
    #pragma unroll
    for (int m = 1; m < 64; m <<= 1)
        sum += __shfl_xor(sum, m, 64);

    float v_mem = membrane_potential[row] * 0.7f + sum;   // wave-broadcast load
    float thr   = adaptive_threshold[row];
    float spike = (v_mem >= thr) ? 1.0f : 0.0f;
    if (lane == 0) {
        out_spikes[row] = spike;
        out_vmem[row]   = v_mem * (1.0f - spike) * 0.3f;
        out_thresh[row] = fminf(fmaxf(thr + (spike - TARGET_RATE) * 0.05f, 0.5f), 5.0f);
    }
}

// Kernel B: one wave per row; pure E->T stream (the float4-copy shape).
// new_trace = clip(E*0.8 + spike*clip(2x,0,1), 0, 3). spike read per row
// (written by kernel A; stream order guarantees visibility). Branch-free:
// spike multiply, exactly round-0's epilogue form.
__global__ __launch_bounds__(256) void snn_trace(
    const float* __restrict__ spike_input,        // [IN_F]
    const float* __restrict__ eligibility_trace,  // [OUT_F, IN_F]
    const float* __restrict__ out_spikes,         // [OUT_F] (input here)
    float* __restrict__ out_trace)                // [OUT_F, IN_F]
{
    const int row  = (blockIdx.x << 2) + (threadIdx.x >> 6);  // wave id = row
    const int lane = threadIdx.x & 63;

    const f32x4* x4 = (const f32x4*)spike_input;
    const f32x4* e4 = (const f32x4*)(eligibility_trace + (size_t)row * IN_F);
    f32x4*       t4 = (f32x4*)(out_trace + (size_t)row * IN_F);

    const float spike = out_spikes[row];          // wave-broadcast, L2-hot

    #pragma unroll 8
    for (int k = 0; k < 32; ++k) {
        int idx = lane + (k << 6);
        f32x4 e = __builtin_nontemporal_load(&e4[idx]);
        f32x4 v = x4[idx];                        // cache-hot
        f32x4 t;
        t.x = fminf(fmaxf(e.x * 0.8f + spike * fminf(fmaxf(v.x * 2.0f, 0.0f), 1.0f), 0.0f), 3.0f);
        t.y = fminf(fmaxf(e.y * 0.8f + spike * fminf(fmaxf(v.y * 2.0f, 0.0f), 1.0f), 0.0f), 3.0f);
        t.z = fminf(fmaxf(e.z * 0.8f + spike * fminf(fmaxf(v.z * 2.0f, 0.0f), 1.0f), 0.0f), 3.0f);
        t.w = fminf(fmaxf(e.w * 0.8f + spike * fminf(fmaxf(v.w * 2.0f, 0.0f), 1.0f), 0.0f), 3.0f);
        __builtin_nontemporal_store(t, &t4[idx]);
    }
}

extern "C" void kernel_launch(void* const* d_in, const int* in_sizes, int n_in,
                              void* d_out, int out_size, void* d_ws, size_t ws_size,
                              hipStream_t stream) {
    const float* spike_input        = (const float*)d_in[0];
    const float* synapse_states     = (const float*)d_in[1];
    const float* membrane_potential = (const float*)d_in[2];
    const float* adaptive_threshold = (const float*)d_in[3];
    const float* eligibility_trace  = (const float*)d_in[4];

    float* out = (float*)d_out;
    float* out_spikes = out;                      // [OUT_F]
    float* out_vmem   = out + OUT_F;              // [OUT_F]
    float* out_thresh = out + 2 * OUT_F;          // [OUT_F]
    float* out_trace  = out + 3 * OUT_F;          // [OUT_F, IN_F]

    // 4 rows (waves) per block -> 2048 blocks each.
    snn_reduce<<<OUT_F / 4, 256, 0, stream>>>(
        spike_input, synapse_states, membrane_potential, adaptive_threshold,
        out_spikes, out_vmem, out_thresh);

    snn_trace<<<OUT_F / 4, 256, 0, stream>>>(
        spike_input, eligibility_trace, out_spikes, out_trace);
}

// Round 6
// 574.674 us; speedup vs baseline: 1.0318x; 1.0156x over previous
//
#include <hip/hip_runtime.h>

#define IN_F 8192
#define OUT_F 8192
#define THRESHOLD_F 50.0f
#define TARGET_RATE 0.1f

// clang-native vector type: required by __builtin_nontemporal_load/store
typedef float f32x4 __attribute__((ext_vector_type(4)));

// One WAVE per output row; 4 waves (4 rows) per 256-thread block; no LDS, no
// barriers.
//
// Round-6: front-loaded E read stream (the round-2/3 design, never measured
// due to infra failures; round-5 confirmed infra healthy).
//
// Why: stores and loads share vmcnt and retire in issue order. An interleaved
// {load e[8] -> wait -> store t[8]} stream (all prior rounds) forces an
// effective vmcnt(0) drain every 8 vectors -- the whole E->T stream (2/3 of
// traffic) runs at queue depth <=8 with periodic full drains (~5.0 TB/s
// observed vs 6.3 copy ceiling). Issuing ALL E loads before ANY store makes
// every wait vmcnt(31-ish): the write tail never drains the read queue.
//   - E loads in TWO 16-vector register batches (hedge VGPR pressure):
//     batch 0 issued right after the last S load (rides out the butterfly +
//     neuron update), batch 1 issued right after the reduce, before batch
//     0's stores.
//   - Cache policy: everything nt (round-1 measured L3-residency for S
//     SLOWER than the nt HBM stream: 202 us vs ~160 us).
//   - Branch-free phase 3 (spike multiply), round-0's proven epilogue form.
__global__ __launch_bounds__(256) void snn_wave_fused(
    const float* __restrict__ spike_input,        // [IN_F]
    const float* __restrict__ synapse_states,     // [OUT_F, IN_F]
    const float* __restrict__ membrane_potential, // [OUT_F]
    const float* __restrict__ adaptive_threshold, // [OUT_F]
    const float* __restrict__ eligibility_trace,  // [OUT_F, IN_F]
    float* __restrict__ out_spikes,               // [OUT_F]
    float* __restrict__ out_vmem,                 // [OUT_F]
    float* __restrict__ out_thresh,               // [OUT_F]
    float* __restrict__ out_trace)                // [OUT_F, IN_F]
{
    const int row  = (blockIdx.x << 2) + (threadIdx.x >> 6);  // wave id = row
    const int lane = threadIdx.x & 63;

    const f32x4* x4 = (const f32x4*)spike_input;
    const f32x4* s4 = (const f32x4*)(synapse_states + (size_t)row * IN_F);
    const f32x4* e4 = (const f32x4*)(eligibility_trace + (size_t)row * IN_F);
    f32x4*       t4 = (f32x4*)(out_trace + (size_t)row * IN_F);

    // ---- Phase 1: current = sum_i (S[row,i] > 50) * clip(2*x[i],0,1) ----
    // Read-only stream: no stores in flight, queue depth bounded only by
    // the unroll window.
    float sum = 0.0f;
    #pragma unroll 8
    for (int k = 0; k < 32; ++k) {
        int idx = lane + (k << 6);                 // f32x4 idx in [0, 2048)
        f32x4 s = __builtin_nontemporal_load(&s4[idx]);  // single-use stream
        f32x4 v = x4[idx];                               // hot in cache
        v.x = fminf(fmaxf(v.x * 2.0f, 0.0f), 1.0f);
        v.y = fminf(fmaxf(v.y * 2.0f, 0.0f), 1.0f);
        v.z = fminf(fmaxf(v.z * 2.0f, 0.0f), 1.0f);
        v.w = fminf(fmaxf(v.w * 2.0f, 0.0f), 1.0f);
        sum += (s.x > THRESHOLD_F ? v.x : 0.0f)
             + (s.y > THRESHOLD_F ? v.y : 0.0f)
             + (s.z > THRESHOLD_F ? v.z : 0.0f)
             + (s.w > THRESHOLD_F ? v.w : 0.0f);
    }

    // ---- Phase 1.5: issue E batch 0 (16 x f32x4 = 64 VGPRs) now.
    // No dependency on sum/spike -> rides out the butterfly + neuron update.
    // Fully static indices after unroll (runtime-indexed ext_vector arrays
    // would go to scratch).
    f32x4 e0[16];
    #pragma unroll
    for (int k = 0; k < 16; ++k)
        e0[k] = __builtin_nontemporal_load(&e4[lane + (k << 6)]);

    // Butterfly reduction: every lane ends with the identical full sum.
    // Needs only S; E batch 0 stays in flight across it.
    #pragma unroll
    for (int m = 1; m < 64; m <<= 1)
        sum += __shfl_xor(sum, m, 64);

    // ---- Phase 2: neuron update (all lanes compute; lane 0 writes) ----
    float v_mem = membrane_potential[row] * 0.7f + sum;   // wave-broadcast load
    float thr   = adaptive_threshold[row];
    float spike = (v_mem >= thr) ? 1.0f : 0.0f;
    if (lane == 0) {
        out_spikes[row] = spike;
        out_vmem[row]   = v_mem * (1.0f - spike) * 0.3f;
        out_thresh[row] = fminf(fmaxf(thr + (spike - TARGET_RATE) * 0.05f, 0.5f), 5.0f);
    }

    // ---- Phase 2.5: issue E batch 1 BEFORE any store of batch 0 ----
    f32x4 e1[16];
    #pragma unroll
    for (int k = 0; k < 16; ++k)
        e1[k] = __builtin_nontemporal_load(&e4[lane + ((k + 16) << 6)]);

    // ---- Phase 3: new_trace[row,i] = clip(E*0.8 + spike*x, 0, 3) ----
    // Pure write tail: all 32 E loads already issued; waiting for e0[k]
    // needs only "outstanding <= 31", which the stores never violate.
    #pragma unroll
    for (int k = 0; k < 16; ++k) {
        int idx = lane + (k << 6);
        f32x4 v = x4[idx];                        // cache-hot
        f32x4 t;
        t.x = fminf(fmaxf(e0[k].x * 0.8f + spike * fminf(fmaxf(v.x * 2.0f, 0.0f), 1.0f), 0.0f), 3.0f);
        t.y = fminf(fmaxf(e0[k].y * 0.8f + spike * fminf(fmaxf(v.y * 2.0f, 0.0f), 1.0f), 0.0f), 3.0f);
        t.z = fminf(fmaxf(e0[k].z * 0.8f + spike * fminf(fmaxf(v.z * 2.0f, 0.0f), 1.0f), 0.0f), 3.0f);
        t.w = fminf(fmaxf(e0[k].w * 0.8f + spike * fminf(fmaxf(v.w * 2.0f, 0.0f), 1.0f), 0.0f), 3.0f);
        __builtin_nontemporal_store(t, &t4[idx]);
    }
    #pragma unroll
    for (int k = 0; k < 16; ++k) {
        int idx = lane + ((k + 16) << 6);
        f32x4 v = x4[idx];
        f32x4 t;
        t.x = fminf(fmaxf(e1[k].x * 0.8f + spike * fminf(fmaxf(v.x * 2.0f, 0.0f), 1.0f), 0.0f), 3.0f);
        t.y = fminf(fmaxf(e1[k].y * 0.8f + spike * fminf(fmaxf(v.y * 2.0f, 0.0f), 1.0f), 0.0f), 3.0f);
        t.z = fminf(fmaxf(e1[k].z * 0.8f + spike * fminf(fmaxf(v.z * 2.0f, 0.0f), 1.0f), 0.0f), 3.0f);
        t.w = fminf(fmaxf(e1[k].w * 0.8f + spike * fminf(fmaxf(v.w * 2.0f, 0.0f), 1.0f), 0.0f), 3.0f);
        __builtin_nontemporal_store(t, &t4[idx]);
    }
}

extern "C" void kernel_launch(void* const* d_in, const int* in_sizes, int n_in,
                              void* d_out, int out_size, void* d_ws, size_t ws_size,
                              hipStream_t stream) {
    const float* spike_input        = (const float*)d_in[0];
    const float* synapse_states     = (const float*)d_in[1];
    const float* membrane_potential = (const float*)d_in[2];
    const float* adaptive_threshold = (const float*)d_in[3];
    const float* eligibility_trace  = (const float*)d_in[4];

    float* out = (float*)d_out;
    float* out_spikes = out;                      // [OUT_F]
    float* out_vmem   = out + OUT_F;              // [OUT_F]
    float* out_thresh = out + 2 * OUT_F;          // [OUT_F]
    float* out_trace  = out + 3 * OUT_F;          // [OUT_F, IN_F]

    // 4 rows (waves) per block -> 2048 blocks.
    snn_wave_fused<<<OUT_F / 4, 256, 0, stream>>>(
        spike_input, synapse_states, membrane_potential, adaptive_threshold,
        eligibility_trace, out_spikes, out_vmem, out_thresh, out_trace);
}